// Round 8
// baseline (574.574 us; speedup 1.0000x reference)
//
#include <hip/hip_runtime.h>
#include <hip/hip_bf16.h>
#include <cstdint>
#include <cstddef>

#define S_LEN 2048
#define HID   2560
#define NHQ   8
#define QKV_N 4096   // (NH + 2*NKV) * D
#define ATT_N 2048   // NH * D
#define WIN   1023
#define SCALE 0.0625f
#define NINF  -3.0e38f

typedef __attribute__((ext_vector_type(8))) short bf16x8;
typedef __attribute__((ext_vector_type(4))) float f32x4;

__device__ __forceinline__ unsigned bf_hi(float f) {
  unsigned u = __builtin_bit_cast(unsigned, f);
  return (u + 0x7FFFu + ((u >> 16) & 1u)) >> 16;   // RNE bf16 bits
}
__device__ __forceinline__ float bf_to_f(unsigned h) {
  return __builtin_bit_cast(float, h << 16);
}
__device__ __forceinline__ void g2l16(const void* g, void* l) {
  __builtin_amdgcn_global_load_lds((const __attribute__((address_space(1))) void*)g,
                                   (__attribute__((address_space(3))) void*)l,
                                   16, 0, 0);
}

// ---------- row-split: X[M][K] f32 -> Xh, Xl [M][K] bf16 ----------
__global__ __launch_bounds__(256) void split_rows(const float* __restrict__ X,
                                                  unsigned short* __restrict__ Xh,
                                                  unsigned short* __restrict__ Xl) {
  const size_t i = ((size_t)blockIdx.x * 256 + threadIdx.x) * 8;
  const float4 v0 = *(const float4*)(X + i);
  const float4 v1 = *(const float4*)(X + i + 4);
  const float f[8] = {v0.x, v0.y, v0.z, v0.w, v1.x, v1.y, v1.z, v1.w};
  unsigned hw[4], lw[4];
  #pragma unroll
  for (int j = 0; j < 4; ++j) {
    const unsigned h0 = bf_hi(f[2 * j]), h1 = bf_hi(f[2 * j + 1]);
    const float r0 = f[2 * j] - bf_to_f(h0), r1 = f[2 * j + 1] - bf_to_f(h1);
    hw[j] = h0 | (h1 << 16);
    lw[j] = bf_hi(r0) | (bf_hi(r1) << 16);
  }
  *(uint4*)(Xh + i) = make_uint4(hw[0], hw[1], hw[2], hw[3]);
  *(uint4*)(Xl + i) = make_uint4(lw[0], lw[1], lw[2], lw[3]);
}

// ---------- split+transpose: W[K][N] f32 -> Th/Tl[N][K] bf16 (hi/lo) ----------
__global__ __launch_bounds__(256) void split_transpose(const float* __restrict__ W,
                                                       unsigned short* __restrict__ Th,
                                                       unsigned short* __restrict__ Tl,
                                                       int K, int N) {
  __shared__ float tile[32][33];
  const int tid = threadIdx.x;
  const int kt = blockIdx.y * 32, nt = blockIdx.x * 32;
  {
    const int r = tid >> 3, c = (tid & 7) * 4;
    const float4 v = *(const float4*)(W + (size_t)(kt + r) * N + nt + c);
    tile[r][c] = v.x; tile[r][c + 1] = v.y; tile[r][c + 2] = v.z; tile[r][c + 3] = v.w;
  }
  __syncthreads();
  const int nl = tid >> 3, k = (tid & 7) * 4;
  unsigned hw[2], lw[2];
  #pragma unroll
  for (int j = 0; j < 2; ++j) {
    const float f0 = tile[k + 2 * j][nl], f1 = tile[k + 2 * j + 1][nl];
    const unsigned h0 = bf_hi(f0), h1 = bf_hi(f1);
    const float r0 = f0 - bf_to_f(h0), r1 = f1 - bf_to_f(h1);
    hw[j] = h0 | (h1 << 16);
    lw[j] = bf_hi(r0) | (bf_hi(r1) << 16);
  }
  *(uint2*)(Th + (size_t)(nt + nl) * K + kt + k) = make_uint2(hw[0], hw[1]);
  *(uint2*)(Tl + (size_t)(nt + nl) * K + kt + k) = make_uint2(lw[0], lw[1]);
}

// ---------- all-bf16 split GEMM: C[M][N] f32 = (Ah+Al)[M][K] @ (Bh+Bl)[N][K]^T ----------
__global__ __launch_bounds__(256) void gemm_bf16_split(
    const unsigned short* __restrict__ Ah, const unsigned short* __restrict__ Al,
    const unsigned short* __restrict__ Bh, const unsigned short* __restrict__ Bl,
    float* __restrict__ C, int M, int N, int K, int nbx) {
  __shared__ __align__(16) unsigned short smem[16384];   // 4 tiles x 128x32 ush = 32 KB

  const int tid = threadIdx.x;
  int bid = blockIdx.x;
  const int cpx = gridDim.x >> 3;                 // grid % 8 == 0 for all calls
  bid = (bid & 7) * cpx + (bid >> 3);             // XCD-contiguous swizzle
  const int bm = (bid / nbx) * 128;
  const int bn = (bid % nbx) * 128;

  const int lane = tid & 63;
  const int wv = tid >> 6;
  const int wr = (wv >> 1) * 64;
  const int wc = (wv & 1) * 64;
  const int frow = lane & 15;
  const int g16 = lane >> 4;

  const int u0 = tid, u1 = tid + 256;
  const int r0 = u0 >> 2, s0 = (u0 & 3) ^ ((r0 >> 1) & 3);
  const int r1 = u1 >> 2, s1 = (u1 & 3) ^ ((r1 >> 1) & 3);

  const unsigned short* a_h = Ah + (size_t)bm * K;
  const unsigned short* a_l = Al + (size_t)bm * K;
  const unsigned short* b_h = Bh + (size_t)bn * K;
  const unsigned short* b_l = Bl + (size_t)bn * K;

  unsigned short* d0 = smem + ((tid & ~63) << 3);
  unsigned short* d1 = smem + 2048 + ((tid & ~63) << 3);

  const int sx = (g16 ^ ((frow >> 1) & 3)) * 8;

  f32x4 acc[4][4] = {};

  for (int k0 = 0; k0 < K; k0 += 32) {
    __syncthreads();
    {
      const size_t o0 = (size_t)r0 * K + k0 + s0 * 8;
      const size_t o1 = (size_t)r1 * K + k0 + s1 * 8;
      g2l16(a_h + o0, d0);
      g2l16(a_h + o1, d1);
      g2l16(a_l + o0, d0 + 4096);
      g2l16(a_l + o1, d1 + 4096);
      g2l16(b_h + o0, d0 + 8192);
      g2l16(b_h + o1, d1 + 8192);
      g2l16(b_l + o0, d0 + 12288);
      g2l16(b_l + o1, d1 + 12288);
    }
    __syncthreads();

    bf16x8 ah[4], al[4], bh[4], bl[4];
    #pragma unroll
    for (int i = 0; i < 4; ++i) {
      ah[i] = *(const bf16x8*)&smem[(wr + i * 16 + frow) * 32 + sx];
      al[i] = *(const bf16x8*)&smem[4096 + (wr + i * 16 + frow) * 32 + sx];
      bh[i] = *(const bf16x8*)&smem[8192 + (wc + i * 16 + frow) * 32 + sx];
      bl[i] = *(const bf16x8*)&smem[12288 + (wc + i * 16 + frow) * 32 + sx];
    }
    #pragma unroll
    for (int i = 0; i < 4; ++i)
      #pragma unroll
      for (int j = 0; j < 4; ++j) {
        acc[i][j] = __builtin_amdgcn_mfma_f32_16x16x32_bf16(ah[i], bh[j], acc[i][j], 0, 0, 0);
        acc[i][j] = __builtin_amdgcn_mfma_f32_16x16x32_bf16(ah[i], bl[j], acc[i][j], 0, 0, 0);
        acc[i][j] = __builtin_amdgcn_mfma_f32_16x16x32_bf16(al[i], bh[j], acc[i][j], 0, 0, 0);
      }
  }

  #pragma unroll
  for (int i = 0; i < 4; ++i) {
    const int row0 = bm + wr + i * 16 + g16 * 4;
    #pragma unroll
    for (int j = 0; j < 4; ++j) {
      const int c = bn + wc + j * 16 + frow;
      #pragma unroll
      for (int r = 0; r < 4; ++r)
        C[(size_t)(row0 + r) * N + c] = acc[i][j][r];
    }
  }
}

// ------- RMSNorm + RoPE -> split-bf16 Q (scaled) / K buffers, MFMA layout -------
__global__ __launch_bounds__(256) void qk_norm_rope_split(
    const float* __restrict__ qkv, const float* __restrict__ cosp,
    const float* __restrict__ sinp, const float* __restrict__ qw,
    const float* __restrict__ kw,
    unsigned short* __restrict__ Qh, unsigned short* __restrict__ Ql,
    unsigned short* __restrict__ Kh, unsigned short* __restrict__ Kl) {
  const int lane = threadIdx.x & 63;
  const int wave = threadIdx.x >> 6;
  const int row  = blockIdx.x * 4 + wave;
  const int s    = row / 12;
  const int c    = row % 12;
  const float* p = qkv + (size_t)s * QKV_N + c * 256;

  float4 x = *(const float4*)(p + lane * 4);
  float ss = x.x * x.x + x.y * x.y + x.z * x.z + x.w * x.w;
  #pragma unroll
  for (int off = 32; off; off >>= 1) ss += __shfl_xor(ss, off);
  const float scale = rsqrtf(ss * (1.0f / 256.0f) + 1e-6f);

  const float* wp = (c < 8) ? qw : kw;
  float4 w4 = *(const float4*)(wp + lane * 4);
  float y0 = x.x * scale * (1.0f + w4.x);
  float y1 = x.y * scale * (1.0f + w4.y);
  float y2 = x.z * scale * (1.0f + w4.z);
  float y3 = x.w * scale * (1.0f + w4.w);

  float z0 = __shfl_xor(y0, 32);
  float z1 = __shfl_xor(y1, 32);
  float z2 = __shfl_xor(y2, 32);
  float z3 = __shfl_xor(y3, 32);
  const float sgn = (lane < 32) ? -1.0f : 1.0f;

  float4 c4 = *(const float4*)(cosp + (size_t)s * 256 + lane * 4);
  float4 s4 = *(const float4*)(sinp + (size_t)s * 256 + lane * 4);
  float o[4];
  o[0] = y0 * c4.x + sgn * z0 * s4.x;
  o[1] = y1 * c4.y + sgn * z1 * s4.y;
  o[2] = y2 * c4.z + sgn * z2 * s4.z;
  o[3] = y3 * c4.w + sgn * z3 * s4.w;

  const float mul = (c < 8) ? SCALE : 1.0f;   // fold softmax scale into Q
  #pragma unroll
  for (int j = 0; j < 4; ++j) o[j] *= mul;

  unsigned h[4], lo[4];
  #pragma unroll
  for (int j = 0; j < 4; ++j) {
    h[j] = bf_hi(o[j]);
    lo[j] = bf_hi(o[j] - bf_to_f(h[j]));
  }
  const size_t off = ((c < 8) ? ((size_t)c * S_LEN + s)
                              : ((size_t)(c - 8) * S_LEN + s)) * 256 + lane * 4;
  unsigned short* dh = (c < 8 ? Qh : Kh) + off;
  unsigned short* dl = (c < 8 ? Ql : Kl) + off;
  *(uint2*)dh = make_uint2(h[0] | (h[1] << 16), h[2] | (h[3] << 16));
  *(uint2*)dl = make_uint2(lo[0] | (lo[1] << 16), lo[2] | (lo[3] << 16));
}

// ---------- V split + transpose: qkv V region -> VT[kvh][256][2048] hi/lo ----------
__global__ __launch_bounds__(256) void v_split_transpose(
    const float* __restrict__ qkv,
    unsigned short* __restrict__ VTh, unsigned short* __restrict__ VTl) {
  __shared__ float tile[32][33];
  const int tid = threadIdx.x;
  const int s0 = blockIdx.x * 32, d0 = blockIdx.y * 32, kvh = blockIdx.z;
  {
    const int r = tid >> 3, c = (tid & 7) * 4;
    const float4 v = *(const float4*)(qkv + (size_t)(s0 + r) * QKV_N + 3072 + kvh * 256 + d0 + c);
    tile[r][c] = v.x; tile[r][c + 1] = v.y; tile[r][c + 2] = v.z; tile[r][c + 3] = v.w;
  }
  __syncthreads();
  const int dd = tid >> 3, sc = (tid & 7) * 4;
  unsigned h[4], lo[4];
  #pragma unroll
  for (int j = 0; j < 4; ++j) {
    const float f = tile[sc + j][dd];
    h[j] = bf_hi(f);
    lo[j] = bf_hi(f - bf_to_f(h[j]));
  }
  const size_t off = ((size_t)kvh * 256 + d0 + dd) * S_LEN + s0 + sc;
  *(uint2*)(VTh + off) = make_uint2(h[0] | (h[1] << 16), h[2] | (h[3] << 16));
  *(uint2*)(VTl + off) = make_uint2(lo[0] | (lo[1] << 16), lo[2] | (lo[3] << 16));
}

// ---------------- split-K MFMA attention, no KV staging (L2-direct) ----------------
// 1 wave per block, 16 q-rows, half the k-window. Grid 2048 decoded for XCD-kvh
// affinity (kvh j -> XCDs {2j,2j+1} under b%8 round-robin). K/V MFMA fragments
// are loaded directly from global (L2-resident after affinity). No barriers.
// Emits unnormalized partial O (f32) + m,l for a combine pass.
__global__ __launch_bounds__(64, 2) void attn_part(
    const unsigned short* __restrict__ Qh, const unsigned short* __restrict__ Ql,
    const unsigned short* __restrict__ Kh, const unsigned short* __restrict__ Kl,
    const unsigned short* __restrict__ VTh, const unsigned short* __restrict__ VTl,
    float* __restrict__ O0, float* __restrict__ O1, float* __restrict__ ML) {
  __shared__ __align__(16) unsigned short smem[1280];   // P hi[16][40] + lo[16][40]

  const int lane = threadIdx.x & 63;
  const int b    = blockIdx.x;
  const int xcd  = b & 7;
  const int kvh  = xcd >> 1;
  const int head = kvh * 2 + ((b >> 3) & 1);
  const int rest = b >> 4;                    // 0..127
  const int kh   = rest & 1;
  const int qt   = ((rest >> 1) << 1) | (xcd & 1);   // 0..127
  const int q0   = qt * 16;
  const int g16  = lane >> 4;      // 0..3
  const int c16  = lane & 15;      // 0..15

  // ---- Q fragments (A-operand), hi/lo, held in registers ----
  bf16x8 qh[8], ql[8];
  {
    const unsigned short* qph = Qh + ((size_t)head * S_LEN + q0 + c16) * 256 + g16 * 8;
    const unsigned short* qpl = Ql + ((size_t)head * S_LEN + q0 + c16) * 256 + g16 * 8;
    #pragma unroll
    for (int dc = 0; dc < 8; ++dc) {
      qh[dc] = *(const bf16x8*)(qph + dc * 32);
      ql[dc] = *(const bf16x8*)(qpl + dc * 32);
    }
  }

  f32x4 o_acc[16] = {};
  float m_run[4], l_run[4];
  #pragma unroll
  for (int r = 0; r < 4; ++r) { m_run[r] = NINF; l_run[r] = 0.0f; }

  const unsigned short* kh_g  = Kh  + (size_t)kvh * S_LEN * 256;
  const unsigned short* kl_g  = Kl  + (size_t)kvh * S_LEN * 256;
  const unsigned short* vth_g = VTh + (size_t)kvh * 256 * S_LEN;
  const unsigned short* vtl_g = VTl + (size_t)kvh * 256 * S_LEN;

  const int kstart = (q0 > WIN) ? ((q0 - WIN) & ~31) : 0;
  const int ntiles = ((q0 + 15 - kstart) >> 5) + 1;
  const int n0 = (ntiles + 1) >> 1;
  const int t_lo = kstart + (kh ? n0 * 32 : 0);
  const int t_hi = kstart + (kh ? ntiles * 32 : n0 * 32);

  for (int t0 = t_lo; t0 < t_hi; t0 += 32) {
    // ---- QK^T: S[16q x 32k], K frags straight from L2 ----
    f32x4 sa[2] = {};
    #pragma unroll
    for (int t = 0; t < 2; ++t) {
      const unsigned short* kph = kh_g + (size_t)(t0 + t * 16 + c16) * 256 + g16 * 8;
      const unsigned short* kpl = kl_g + (size_t)(t0 + t * 16 + c16) * 256 + g16 * 8;
      #pragma unroll
      for (int dc = 0; dc < 8; ++dc) {
        const bf16x8 kfh = *(const bf16x8*)(kph + dc * 32);
        const bf16x8 kfl = *(const bf16x8*)(kpl + dc * 32);
        sa[t] = __builtin_amdgcn_mfma_f32_16x16x32_bf16(qh[dc], kfh, sa[t], 0, 0, 0);
        sa[t] = __builtin_amdgcn_mfma_f32_16x16x32_bf16(qh[dc], kfl, sa[t], 0, 0, 0);
        sa[t] = __builtin_amdgcn_mfma_f32_16x16x32_bf16(ql[dc], kfh, sa[t], 0, 0, 0);
      }
    }

    // ---- online softmax (row = g16*4+r, key col = c16 + 16t) ----
    const int k0c = t0 + c16;
    #pragma unroll
    for (int r = 0; r < 4; ++r) {
      const int q = q0 + g16 * 4 + r;
      const bool v0 = (k0c <= q) && (q - k0c <= WIN);
      const bool v1 = (k0c + 16 <= q) && (q - (k0c + 16) <= WIN);
      float s0 = v0 ? sa[0][r] : NINF;
      float s1 = v1 ? sa[1][r] : NINF;
      float mx = fmaxf(s0, s1);
      #pragma unroll
      for (int off = 8; off; off >>= 1) mx = fmaxf(mx, __shfl_xor(mx, off));
      const float m_new = fmaxf(m_run[r], mx);
      const float rs = __expf(m_run[r] - m_new);
      const float p0 = v0 ? __expf(s0 - m_new) : 0.0f;
      const float p1 = v1 ? __expf(s1 - m_new) : 0.0f;
      float psum = p0 + p1;
      #pragma unroll
      for (int off = 8; off; off >>= 1) psum += __shfl_xor(psum, off);
      l_run[r] = l_run[r] * rs + psum;
      m_run[r] = m_new;
      #pragma unroll
      for (int dt = 0; dt < 16; ++dt) o_acc[dt][r] *= rs;
      const int pro = (g16 * 4 + r) * 40;
      const unsigned h0 = bf_hi(p0), h1 = bf_hi(p1);
      smem[pro + c16]       = (unsigned short)h0;
      smem[pro + 16 + c16]  = (unsigned short)h1;
      smem[640 + pro + c16]      = (unsigned short)bf_hi(p0 - bf_to_f(h0));
      smem[640 + pro + 16 + c16] = (unsigned short)bf_hi(p1 - bf_to_f(h1));
    }

    // ---- PV: V frags straight from L2 ----
    const bf16x8 pah = *(const bf16x8*)&smem[c16 * 40 + g16 * 8];
    const bf16x8 pal = *(const bf16x8*)&smem[640 + c16 * 40 + g16 * 8];
    #pragma unroll
    for (int dt = 0; dt < 16; ++dt) {
      const bf16x8 vfh = *(const bf16x8*)(vth_g + (size_t)(dt * 16 + c16) * S_LEN + t0 + g16 * 8);
      const bf16x8 vfl = *(const bf16x8*)(vtl_g + (size_t)(dt * 16 + c16) * S_LEN + t0 + g16 * 8);
      o_acc[dt] = __builtin_amdgcn_mfma_f32_16x16x32_bf16(pah, vfh, o_acc[dt], 0, 0, 0);
      o_acc[dt] = __builtin_amdgcn_mfma_f32_16x16x32_bf16(pah, vfl, o_acc[dt], 0, 0, 0);
      o_acc[dt] = __builtin_amdgcn_mfma_f32_16x16x32_bf16(pal, vfh, o_acc[dt], 0, 0, 0);
    }
  }

  // ---- epilogue: unnormalized partial O + m,l ----
  float* op = (kh ? O1 : O0) + ((size_t)head * S_LEN + q0) * 256;
  #pragma unroll
  for (int r = 0; r < 4; ++r) {
    const int qloc = g16 * 4 + r;
    #pragma unroll
    for (int dt = 0; dt < 16; ++dt)
      op[(size_t)qloc * 256 + dt * 16 + c16] = o_acc[dt][r];
  }
  if (c16 == 0) {
    float* mlb = ML + kh * 32768;
    #pragma unroll
    for (int r = 0; r < 4; ++r) {
      const int q = q0 + g16 * 4 + r;
      mlb[head * S_LEN + q]         = m_run[r];
      mlb[16384 + head * S_LEN + q] = l_run[r];
    }
  }
}

// ---------- combine the two k-half partials -> split-bf16 attn output ----------
__global__ __launch_bounds__(256) void attn_combine(
    const float* __restrict__ O0, const float* __restrict__ O1,
    const float* __restrict__ ML,
    unsigned short* __restrict__ Oh, unsigned short* __restrict__ Ol) {
  const int lane = threadIdx.x & 63;
  const int wave = threadIdx.x >> 6;
  const int row  = blockIdx.x * 4 + wave;     // head*2048 + s
  const int head = row >> 11, s = row & 2047;
  const float m0 = ML[row],         l0 = ML[16384 + row];
  const float m1 = ML[32768 + row], l1 = ML[49152 + row];
  const float m  = fmaxf(m0, m1);
  const float w0 = __expf(m0 - m), w1 = __expf(m1 - m);
  const float inv = 1.0f / (l0 * w0 + l1 * w1);
  const float4 a = *(const float4*)(O0 + (size_t)row * 256 + lane * 4);
  const float4 bq = *(const float4*)(O1 + (size_t)row * 256 + lane * 4);
  float o[4] = {(a.x * w0 + bq.x * w1) * inv, (a.y * w0 + bq.y * w1) * inv,
                (a.z * w0 + bq.z * w1) * inv, (a.w * w0 + bq.w * w1) * inv};
  unsigned h[4], lo[4];
  #pragma unroll
  for (int j = 0; j < 4; ++j) {
    h[j] = bf_hi(o[j]);
    lo[j] = bf_hi(o[j] - bf_to_f(h[j]));
  }
  const size_t rowo = (size_t)s * ATT_N + head * 256 + lane * 4;
  *(uint2*)(Oh + rowo) = make_uint2(h[0] | (h[1] << 16), h[2] | (h[3] << 16));
  *(uint2*)(Ol + rowo) = make_uint2(lo[0] | (lo[1] << 16), lo[2] | (lo[3] << 16));
}

extern "C" void kernel_launch(void* const* d_in, const int* in_sizes, int n_in,
                              void* d_out, int out_size, void* d_ws, size_t ws_size,
                              hipStream_t stream) {
  const float* hs    = (const float*)d_in[0];
  const float* cosp  = (const float*)d_in[1];
  const float* sinp  = (const float*)d_in[2];
  const float* w_qkv = (const float*)d_in[3];   // (2560, 4096)
  const float* w_o   = (const float*)d_in[4];   // (2048, 2560)
  const float* qw    = (const float*)d_in[5];
  const float* kw    = (const float*)d_in[6];

  const size_t MB = 1024 * 1024;
  char* ws = (char*)d_ws;
  // workspace map (peak 72 MiB, liveness-overlaid):
  float* qkv = (float*)ws;                               // [0,32M): gemm1 out, dead after preps
  unsigned short* wh = (unsigned short*)(ws + 32 * MB);  // [32,52M): w_qkv hi, dead after gemm1
  unsigned short* wl = (unsigned short*)(ws + 52 * MB);  // [52,72M)
  unsigned short* Qh = (unsigned short*)(ws + 32 * MB);  // [32,40M), dead after attn
  unsigned short* Ql = (unsigned short*)(ws + 40 * MB);  // [40,48M)
  unsigned short* Kh = (unsigned short*)(ws + 48 * MB);  // [48,52M)
  unsigned short* Kl = (unsigned short*)(ws + 52 * MB);  // [52,56M)
  unsigned short* VTh = (unsigned short*)(ws + 56 * MB); // [56,60M)
  unsigned short* VTl = (unsigned short*)(ws + 60 * MB); // [60,64M)
  float* O0 = (float*)ws;                                // [0,16M): qkv dead by then
  float* MLp = (float*)(ws + 16 * MB);                   // [16,16.25M)
  unsigned short* Oh = (unsigned short*)(ws + 32 * MB);  // [32,40M): Qh dead after attn
  unsigned short* Ol = (unsigned short*)(ws + 40 * MB);  // [40,48M)
  unsigned short* oh = (unsigned short*)(ws + 48 * MB);  // [48,58M): K/VT dead
  unsigned short* ol = (unsigned short*)(ws + 58 * MB);  // [58,68M)
  // d_out doubles as scratch: hs split (dead after gemm1), then khalf-1 partial
  unsigned short* Ahs = (unsigned short*)d_out;
  unsigned short* Als = Ahs + (size_t)S_LEN * HID;
  float* O1 = (float*)d_out;                             // 16M of 20.97M
  float* out = (float*)d_out;

  // 1) hs -> split bf16 (into d_out scratch)
  split_rows<<<(S_LEN * HID) / (256 * 8), 256, 0, stream>>>(hs, Ahs, Als);
  // 2) w_qkv -> split^T
  split_transpose<<<dim3(QKV_N / 32, HID / 32), 256, 0, stream>>>(
      w_qkv, wh, wl, HID, QKV_N);
  // 3) qkv = hs @ w_qkv  (all-bf16 split MFMA, g2l16-staged)
  gemm_bf16_split<<<(S_LEN / 128) * (QKV_N / 128), 256, 0, stream>>>(
      Ahs, Als, wh, wl, qkv, S_LEN, QKV_N, HID, QKV_N / 128);
  // 4) norm+rope -> Q/K split bf16 (SCALE folded into Q)
  qk_norm_rope_split<<<(S_LEN * 12) / 4, 256, 0, stream>>>(
      qkv, cosp, sinp, qw, kw, Qh, Ql, Kh, Kl);
  // 5) V -> split + transpose
  v_split_transpose<<<dim3(S_LEN / 32, 256 / 32, 4), 256, 0, stream>>>(
      qkv, VTh, VTl);
  // 6) split-K attention partials (no staging, L2-direct, XCD-affine)
  attn_part<<<2048, 64, 0, stream>>>(Qh, Ql, Kh, Kl, VTh, VTl, O0, O1, MLp);
  // 7) combine -> split-bf16 attn output (over dead Qh/Ql)
  attn_combine<<<(S_LEN * NHQ) / 4, 256, 0, stream>>>(O0, O1, MLp, Oh, Ol);
  // 8) w_o -> split^T (over dead K/VT)
  split_transpose<<<dim3(HID / 32, ATT_N / 32), 256, 0, stream>>>(
      w_o, oh, ol, ATT_N, HID);
  // 9) out = attn @ w_o
  gemm_bf16_split<<<(S_LEN / 128) * (HID / 128), 256, 0, stream>>>(
      Oh, Ol, oh, ol, out, S_LEN, HID, ATT_N, HID / 128);
}

// Round 9
// 535.823 us; speedup vs baseline: 1.0723x; 1.0723x over previous
//
#include <hip/hip_runtime.h>
#include <hip/hip_bf16.h>
#include <cstdint>
#include <cstddef>

#define S_LEN 2048
#define HID   2560
#define NHQ   8
#define QKV_N 4096   // (NH + 2*NKV) * D
#define ATT_N 2048   // NH * D
#define WIN   1023
#define SCALE 0.0625f
#define NINF  -3.0e38f

typedef __attribute__((ext_vector_type(8))) short bf16x8;
typedef __attribute__((ext_vector_type(4))) float f32x4;

__device__ __forceinline__ unsigned bf_hi(float f) {
  unsigned u = __builtin_bit_cast(unsigned, f);
  return (u + 0x7FFFu + ((u >> 16) & 1u)) >> 16;   // RNE bf16 bits
}
__device__ __forceinline__ float bf_to_f(unsigned h) {
  return __builtin_bit_cast(float, h << 16);
}
__device__ __forceinline__ void g2l16(const void* g, void* l) {
  __builtin_amdgcn_global_load_lds((const __attribute__((address_space(1))) void*)g,
                                   (__attribute__((address_space(3))) void*)l,
                                   16, 0, 0);
}

// ---------- row-split: X[M][K] f32 -> Xh, Xl [M][K] bf16 ----------
__global__ __launch_bounds__(256) void split_rows(const float* __restrict__ X,
                                                  unsigned short* __restrict__ Xh,
                                                  unsigned short* __restrict__ Xl) {
  const size_t i = ((size_t)blockIdx.x * 256 + threadIdx.x) * 8;
  const float4 v0 = *(const float4*)(X + i);
  const float4 v1 = *(const float4*)(X + i + 4);
  const float f[8] = {v0.x, v0.y, v0.z, v0.w, v1.x, v1.y, v1.z, v1.w};
  unsigned hw[4], lw[4];
  #pragma unroll
  for (int j = 0; j < 4; ++j) {
    const unsigned h0 = bf_hi(f[2 * j]), h1 = bf_hi(f[2 * j + 1]);
    const float r0 = f[2 * j] - bf_to_f(h0), r1 = f[2 * j + 1] - bf_to_f(h1);
    hw[j] = h0 | (h1 << 16);
    lw[j] = bf_hi(r0) | (bf_hi(r1) << 16);
  }
  *(uint4*)(Xh + i) = make_uint4(hw[0], hw[1], hw[2], hw[3]);
  *(uint4*)(Xl + i) = make_uint4(lw[0], lw[1], lw[2], lw[3]);
}

// ---------- split+transpose: W[K][N] f32 -> Th/Tl[N][K] bf16 (hi/lo) ----------
__global__ __launch_bounds__(256) void split_transpose(const float* __restrict__ W,
                                                       unsigned short* __restrict__ Th,
                                                       unsigned short* __restrict__ Tl,
                                                       int K, int N) {
  __shared__ float tile[32][33];
  const int tid = threadIdx.x;
  const int kt = blockIdx.y * 32, nt = blockIdx.x * 32;
  {
    const int r = tid >> 3, c = (tid & 7) * 4;
    const float4 v = *(const float4*)(W + (size_t)(kt + r) * N + nt + c);
    tile[r][c] = v.x; tile[r][c + 1] = v.y; tile[r][c + 2] = v.z; tile[r][c + 3] = v.w;
  }
  __syncthreads();
  const int nl = tid >> 3, k = (tid & 7) * 4;
  unsigned hw[2], lw[2];
  #pragma unroll
  for (int j = 0; j < 2; ++j) {
    const float f0 = tile[k + 2 * j][nl], f1 = tile[k + 2 * j + 1][nl];
    const unsigned h0 = bf_hi(f0), h1 = bf_hi(f1);
    const float r0 = f0 - bf_to_f(h0), r1 = f1 - bf_to_f(h1);
    hw[j] = h0 | (h1 << 16);
    lw[j] = bf_hi(r0) | (bf_hi(r1) << 16);
  }
  *(uint2*)(Th + (size_t)(nt + nl) * K + kt + k) = make_uint2(hw[0], hw[1]);
  *(uint2*)(Tl + (size_t)(nt + nl) * K + kt + k) = make_uint2(lw[0], lw[1]);
}

// ---------- all-bf16 split GEMM, 2-phase double-buffered staging ----------
// C[M][N] f32 = (Ah+Al)[M][K] @ (Bh+Bl)[N][K]^T. 128x128x32 tile, 4 waves,
// 4x4 frags, 3-term split MFMA. Per K-step: issue next-tile g2l16 BEFORE
// ds_read+MFMA of current tile; ONE barrier per step (T3-minimum pattern).
__global__ __launch_bounds__(256) void gemm_bf16_split(
    const unsigned short* __restrict__ Ah, const unsigned short* __restrict__ Al,
    const unsigned short* __restrict__ Bh, const unsigned short* __restrict__ Bl,
    float* __restrict__ C, int M, int N, int K, int nbx) {
  __shared__ __align__(16) unsigned short smem[32768];   // 2 banks x 32 KB

  const int tid = threadIdx.x;
  int bid = blockIdx.x;
  const int cpx = gridDim.x >> 3;                 // grid % 8 == 0 for all calls
  bid = (bid & 7) * cpx + (bid >> 3);             // XCD-contiguous swizzle
  const int bm = (bid / nbx) * 128;
  const int bn = (bid % nbx) * 128;

  const int lane = tid & 63;
  const int wv = tid >> 6;
  const int wr = (wv >> 1) * 64;
  const int wc = (wv & 1) * 64;
  const int frow = lane & 15;
  const int g16 = lane >> 4;

  const int u0 = tid, u1 = tid + 256;
  const int r0 = u0 >> 2, s0 = (u0 & 3) ^ ((r0 >> 1) & 3);
  const int r1 = u1 >> 2, s1 = (u1 & 3) ^ ((r1 >> 1) & 3);

  const unsigned short* a_h = Ah + (size_t)bm * K;
  const unsigned short* a_l = Al + (size_t)bm * K;
  const unsigned short* b_h = Bh + (size_t)bn * K;
  const unsigned short* b_l = Bl + (size_t)bn * K;

  const int db0 = (tid & ~63) << 3;         // wave-uniform dest offsets (ushorts)
  const int sx = (g16 ^ ((frow >> 1) & 3)) * 8;

  f32x4 acc[4][4] = {};

#define STAGE(bank, kk)                                                     \
  {                                                                         \
    unsigned short* sb = smem + (bank) * 16384;                             \
    unsigned short* dd0 = sb + db0;                                         \
    unsigned short* dd1 = sb + 2048 + db0;                                  \
    const size_t o0 = (size_t)r0 * K + (kk) + s0 * 8;                       \
    const size_t o1 = (size_t)r1 * K + (kk) + s1 * 8;                       \
    g2l16(a_h + o0, dd0);          g2l16(a_h + o1, dd1);                    \
    g2l16(a_l + o0, dd0 + 4096);   g2l16(a_l + o1, dd1 + 4096);             \
    g2l16(b_h + o0, dd0 + 8192);   g2l16(b_h + o1, dd1 + 8192);             \
    g2l16(b_l + o0, dd0 + 12288);  g2l16(b_l + o1, dd1 + 12288);            \
  }

  STAGE(0, 0);
  int cur = 0;
  for (int k0 = 0; k0 < K; k0 += 32) {
    __syncthreads();                       // drains cur's loads; prev reads done
    if (k0 + 32 < K) STAGE(cur ^ 1, k0 + 32);   // next tile flies under MFMA

    const unsigned short* sb = smem + cur * 16384;
    bf16x8 ah[4], al[4], bh[4], bl[4];
    #pragma unroll
    for (int i = 0; i < 4; ++i) {
      ah[i] = *(const bf16x8*)&sb[(wr + i * 16 + frow) * 32 + sx];
      al[i] = *(const bf16x8*)&sb[4096 + (wr + i * 16 + frow) * 32 + sx];
      bh[i] = *(const bf16x8*)&sb[8192 + (wc + i * 16 + frow) * 32 + sx];
      bl[i] = *(const bf16x8*)&sb[12288 + (wc + i * 16 + frow) * 32 + sx];
    }
    #pragma unroll
    for (int i = 0; i < 4; ++i)
      #pragma unroll
      for (int j = 0; j < 4; ++j) {
        acc[i][j] = __builtin_amdgcn_mfma_f32_16x16x32_bf16(ah[i], bh[j], acc[i][j], 0, 0, 0);
        acc[i][j] = __builtin_amdgcn_mfma_f32_16x16x32_bf16(ah[i], bl[j], acc[i][j], 0, 0, 0);
        acc[i][j] = __builtin_amdgcn_mfma_f32_16x16x32_bf16(al[i], bh[j], acc[i][j], 0, 0, 0);
      }
    cur ^= 1;
  }
#undef STAGE

  #pragma unroll
  for (int i = 0; i < 4; ++i) {
    const int row0 = bm + wr + i * 16 + g16 * 4;
    #pragma unroll
    for (int j = 0; j < 4; ++j) {
      const int c = bn + wc + j * 16 + frow;
      #pragma unroll
      for (int r = 0; r < 4; ++r)
        C[(size_t)(row0 + r) * N + c] = acc[i][j][r];
    }
  }
}

// ------- RMSNorm + RoPE -> split-bf16 Q (scaled) / K buffers, MFMA layout -------
__global__ __launch_bounds__(256) void qk_norm_rope_split(
    const float* __restrict__ qkv, const float* __restrict__ cosp,
    const float* __restrict__ sinp, const float* __restrict__ qw,
    const float* __restrict__ kw,
    unsigned short* __restrict__ Qh, unsigned short* __restrict__ Ql,
    unsigned short* __restrict__ Kh, unsigned short* __restrict__ Kl) {
  const int lane = threadIdx.x & 63;
  const int wave = threadIdx.x >> 6;
  const int row  = blockIdx.x * 4 + wave;
  const int s    = row / 12;
  const int c    = row % 12;
  const float* p = qkv + (size_t)s * QKV_N + c * 256;

  float4 x = *(const float4*)(p + lane * 4);
  float ss = x.x * x.x + x.y * x.y + x.z * x.z + x.w * x.w;
  #pragma unroll
  for (int off = 32; off; off >>= 1) ss += __shfl_xor(ss, off);
  const float scale = rsqrtf(ss * (1.0f / 256.0f) + 1e-6f);

  const float* wp = (c < 8) ? qw : kw;
  float4 w4 = *(const float4*)(wp + lane * 4);
  float y0 = x.x * scale * (1.0f + w4.x);
  float y1 = x.y * scale * (1.0f + w4.y);
  float y2 = x.z * scale * (1.0f + w4.z);
  float y3 = x.w * scale * (1.0f + w4.w);

  float z0 = __shfl_xor(y0, 32);
  float z1 = __shfl_xor(y1, 32);
  float z2 = __shfl_xor(y2, 32);
  float z3 = __shfl_xor(y3, 32);
  const float sgn = (lane < 32) ? -1.0f : 1.0f;

  float4 c4 = *(const float4*)(cosp + (size_t)s * 256 + lane * 4);
  float4 s4 = *(const float4*)(sinp + (size_t)s * 256 + lane * 4);
  float o[4];
  o[0] = y0 * c4.x + sgn * z0 * s4.x;
  o[1] = y1 * c4.y + sgn * z1 * s4.y;
  o[2] = y2 * c4.z + sgn * z2 * s4.z;
  o[3] = y3 * c4.w + sgn * z3 * s4.w;

  const float mul = (c < 8) ? SCALE : 1.0f;   // fold softmax scale into Q
  #pragma unroll
  for (int j = 0; j < 4; ++j) o[j] *= mul;

  unsigned h[4], lo[4];
  #pragma unroll
  for (int j = 0; j < 4; ++j) {
    h[j] = bf_hi(o[j]);
    lo[j] = bf_hi(o[j] - bf_to_f(h[j]));
  }
  const size_t off = ((c < 8) ? ((size_t)c * S_LEN + s)
                              : ((size_t)(c - 8) * S_LEN + s)) * 256 + lane * 4;
  unsigned short* dh = (c < 8 ? Qh : Kh) + off;
  unsigned short* dl = (c < 8 ? Ql : Kl) + off;
  *(uint2*)dh = make_uint2(h[0] | (h[1] << 16), h[2] | (h[3] << 16));
  *(uint2*)dl = make_uint2(lo[0] | (lo[1] << 16), lo[2] | (lo[3] << 16));
}

// ---------- V split + transpose: qkv V region -> VT[kvh][256][2048] hi/lo ----------
__global__ __launch_bounds__(256) void v_split_transpose(
    const float* __restrict__ qkv,
    unsigned short* __restrict__ VTh, unsigned short* __restrict__ VTl) {
  __shared__ float tile[32][33];
  const int tid = threadIdx.x;
  const int s0 = blockIdx.x * 32, d0 = blockIdx.y * 32, kvh = blockIdx.z;
  {
    const int r = tid >> 3, c = (tid & 7) * 4;
    const float4 v = *(const float4*)(qkv + (size_t)(s0 + r) * QKV_N + 3072 + kvh * 256 + d0 + c);
    tile[r][c] = v.x; tile[r][c + 1] = v.y; tile[r][c + 2] = v.z; tile[r][c + 3] = v.w;
  }
  __syncthreads();
  const int dd = tid >> 3, sc = (tid & 7) * 4;
  unsigned h[4], lo[4];
  #pragma unroll
  for (int j = 0; j < 4; ++j) {
    const float f = tile[sc + j][dd];
    h[j] = bf_hi(f);
    lo[j] = bf_hi(f - bf_to_f(h[j]));
  }
  const size_t off = ((size_t)kvh * 256 + d0 + dd) * S_LEN + s0 + sc;
  *(uint2*)(VTh + off) = make_uint2(h[0] | (h[1] << 16), h[2] | (h[3] << 16));
  *(uint2*)(VTl + off) = make_uint2(lo[0] | (lo[1] << 16), lo[2] | (lo[3] << 16));
}

// ------- split-K MFMA attention: K LDS-staged, V L2-direct, 2 waves/block -------
// 1024 blocks = (head 8) x (q-tile 64 of 32 rows) x (k-half 2), decoded for
// XCD-kvh affinity (kvh j -> XCDs {2j,2j+1}). K hi/lo staged (37.9 KB LDS ->
// 4 blocks/CU = 8 waves/CU); V fragments straight from L2. Partials + m,l out.
__global__ __launch_bounds__(128, 2) void attn_part(
    const unsigned short* __restrict__ Qh, const unsigned short* __restrict__ Ql,
    const unsigned short* __restrict__ Kh, const unsigned short* __restrict__ Kl,
    const unsigned short* __restrict__ VTh, const unsigned short* __restrict__ VTl,
    float* __restrict__ O0, float* __restrict__ O1, float* __restrict__ ML) {
  __shared__ __align__(16) unsigned short smem[18944];   // K 32KB + P 2x2.5KB

  const int tid  = threadIdx.x;
  const int lane = tid & 63;
  const int wv   = __builtin_amdgcn_readfirstlane(tid >> 6);
  const int b    = blockIdx.x;
  const int xcd  = b & 7;
  const int kvh  = xcd >> 1;
  const int head = kvh * 2 + ((b >> 3) & 1);
  const int kh   = (b >> 4) & 1;
  const int qt   = (((b >> 5) << 1) | (xcd & 1));   // 0..63
  const int q0   = qt * 32;
  const int g16  = lane >> 4;      // 0..3
  const int c16  = lane & 15;      // 0..15
  const int rmin = q0 + wv * 16;

  // ---- Q fragments (A-operand), hi/lo, in registers ----
  bf16x8 qh[8], ql[8];
  {
    const unsigned short* qph = Qh + ((size_t)head * S_LEN + rmin + c16) * 256 + g16 * 8;
    const unsigned short* qpl = Ql + ((size_t)head * S_LEN + rmin + c16) * 256 + g16 * 8;
    #pragma unroll
    for (int dc = 0; dc < 8; ++dc) {
      qh[dc] = *(const bf16x8*)(qph + dc * 32);
      ql[dc] = *(const bf16x8*)(qpl + dc * 32);
    }
  }

  f32x4 o_acc[16] = {};
  float m_run[4], l_run[4];
  #pragma unroll
  for (int r = 0; r < 4; ++r) { m_run[r] = NINF; l_run[r] = 0.0f; }

  const unsigned short* kh_g  = Kh  + (size_t)kvh * S_LEN * 256;
  const unsigned short* kl_g  = Kl  + (size_t)kvh * S_LEN * 256;
  const unsigned short* vth_g = VTh + (size_t)kvh * 256 * S_LEN;
  const unsigned short* vtl_g = VTl + (size_t)kvh * 256 * S_LEN;

  const int kstart = (q0 > WIN) ? ((q0 - WIN) & ~31) : 0;
  const int ntiles = ((q0 + 31 - kstart) >> 5) + 1;
  const int n0 = (ntiles + 1) >> 1;
  const int t_lo = kstart + (kh ? n0 * 32 : 0);
  const int t_hi = kstart + (kh ? ntiles * 32 : n0 * 32);

  const int PB = 16384 + wv * 1280;          // per-wave P region (ushort idx)

  for (int t0 = t_lo; t0 < t_hi; t0 += 32) {
    // ---- stage K tile 32x256 hi/lo (slot ^= row&7 source swizzle) ----
    __syncthreads();                         // prior tile's LDS reads done
    {
      char* lbase = (char*)smem + ((tid & ~63) << 4);
      #pragma unroll
      for (int i = 0; i < 8; ++i) {          // K hi -> bytes [0,16K)
        const int uu = i * 128 + tid, row = uu >> 5, sl = uu & 31;
        g2l16(kh_g + (size_t)(t0 + row) * 256 + ((sl ^ (row & 7)) * 8),
              lbase + i * 2048);
      }
      #pragma unroll
      for (int i = 0; i < 8; ++i) {          // K lo -> bytes [16K,32K)
        const int uu = i * 128 + tid, row = uu >> 5, sl = uu & 31;
        g2l16(kl_g + (size_t)(t0 + row) * 256 + ((sl ^ (row & 7)) * 8),
              lbase + 16384 + i * 2048);
      }
    }
    __syncthreads();                         // drain -> K tile ready

    // ---- QK^T: S[16q x 32k], 3-term split MFMA from LDS ----
    f32x4 sa[2] = {};
    #pragma unroll
    for (int t = 0; t < 2; ++t) {
      const int krow = t * 16 + c16;
      const int swz = krow & 7;
      #pragma unroll
      for (int dc = 0; dc < 8; ++dc) {
        const int sl = ((dc * 4 + g16) ^ swz) * 16;
        const bf16x8 kfh = *(const bf16x8*)((const char*)smem + krow * 512 + sl);
        const bf16x8 kfl = *(const bf16x8*)((const char*)smem + 16384 + krow * 512 + sl);
        sa[t] = __builtin_amdgcn_mfma_f32_16x16x32_bf16(qh[dc], kfh, sa[t], 0, 0, 0);
        sa[t] = __builtin_amdgcn_mfma_f32_16x16x32_bf16(qh[dc], kfl, sa[t], 0, 0, 0);
        sa[t] = __builtin_amdgcn_mfma_f32_16x16x32_bf16(ql[dc], kfh, sa[t], 0, 0, 0);
      }
    }

    // ---- online softmax (row = g16*4+r, key col = c16 + 16t) ----
    const int k0c = t0 + c16;
    #pragma unroll
    for (int r = 0; r < 4; ++r) {
      const int q = rmin + g16 * 4 + r;
      const bool v0 = (k0c <= q) && (q - k0c <= WIN);
      const bool v1 = (k0c + 16 <= q) && (q - (k0c + 16) <= WIN);
      float s0 = v0 ? sa[0][r] : NINF;
      float s1 = v1 ? sa[1][r] : NINF;
      float mx = fmaxf(s0, s1);
      #pragma unroll
      for (int off = 8; off; off >>= 1) mx = fmaxf(mx, __shfl_xor(mx, off));
      const float m_new = fmaxf(m_run[r], mx);
      const float rs = __expf(m_run[r] - m_new);
      const float p0 = v0 ? __expf(s0 - m_new) : 0.0f;
      const float p1 = v1 ? __expf(s1 - m_new) : 0.0f;
      float psum = p0 + p1;
      #pragma unroll
      for (int off = 8; off; off >>= 1) psum += __shfl_xor(psum, off);
      l_run[r] = l_run[r] * rs + psum;
      m_run[r] = m_new;
      #pragma unroll
      for (int dt = 0; dt < 16; ++dt) o_acc[dt][r] *= rs;
      const int pro = PB + (g16 * 4 + r) * 40;
      const unsigned h0 = bf_hi(p0), h1 = bf_hi(p1);
      smem[pro + c16]       = (unsigned short)h0;
      smem[pro + 16 + c16]  = (unsigned short)h1;
      smem[640 + pro + c16]      = (unsigned short)bf_hi(p0 - bf_to_f(h0));
      smem[640 + pro + 16 + c16] = (unsigned short)bf_hi(p1 - bf_to_f(h1));
    }

    // ---- PV: V fragments straight from L2 (wave-private P, no barrier) ----
    const bf16x8 pah = *(const bf16x8*)&smem[PB + c16 * 40 + g16 * 8];
    const bf16x8 pal = *(const bf16x8*)&smem[PB + 640 + c16 * 40 + g16 * 8];
    #pragma unroll
    for (int dt = 0; dt < 16; ++dt) {
      const bf16x8 vfh = *(const bf16x8*)(vth_g + (size_t)(dt * 16 + c16) * S_LEN + t0 + g16 * 8);
      const bf16x8 vfl = *(const bf16x8*)(vtl_g + (size_t)(dt * 16 + c16) * S_LEN + t0 + g16 * 8);
      o_acc[dt] = __builtin_amdgcn_mfma_f32_16x16x32_bf16(pah, vfh, o_acc[dt], 0, 0, 0);
      o_acc[dt] = __builtin_amdgcn_mfma_f32_16x16x32_bf16(pah, vfl, o_acc[dt], 0, 0, 0);
      o_acc[dt] = __builtin_amdgcn_mfma_f32_16x16x32_bf16(pal, vfh, o_acc[dt], 0, 0, 0);
    }
  }

  // ---- epilogue: unnormalized partial O + m,l (unconditional) ----
  float* op = (kh ? O1 : O0) + ((size_t)head * S_LEN + rmin) * 256;
  #pragma unroll
  for (int r = 0; r < 4; ++r) {
    const int qloc = g16 * 4 + r;
    #pragma unroll
    for (int dt = 0; dt < 16; ++dt)
      op[(size_t)qloc * 256 + dt * 16 + c16] = o_acc[dt][r];
  }
  if (c16 == 0) {
    float* mlb = ML + kh * 32768;
    #pragma unroll
    for (int r = 0; r < 4; ++r) {
      const int q = rmin + g16 * 4 + r;
      mlb[head * S_LEN + q]         = m_run[r];
      mlb[16384 + head * S_LEN + q] = l_run[r];
    }
  }
}

// ---------- combine the two k-half partials -> split-bf16 attn output ----------
__global__ __launch_bounds__(256) void attn_combine(
    const float* __restrict__ O0, const float* __restrict__ O1,
    const float* __restrict__ ML,
    unsigned short* __restrict__ Oh, unsigned short* __restrict__ Ol) {
  const int lane = threadIdx.x & 63;
  const int wave = threadIdx.x >> 6;
  const int row  = blockIdx.x * 4 + wave;     // head*2048 + s
  const int head = row >> 11, s = row & 2047;
  const float m0 = ML[row],         l0 = ML[16384 + row];
  const float m1 = ML[32768 + row], l1 = ML[49152 + row];
  const float m  = fmaxf(m0, m1);
  const float w0 = __expf(m0 - m), w1 = __expf(m1 - m);
  const float inv = 1.0f / (l0 * w0 + l1 * w1);
  const float4 a = *(const float4*)(O0 + (size_t)row * 256 + lane * 4);
  const float4 bq = *(const float4*)(O1 + (size_t)row * 256 + lane * 4);
  float o[4] = {(a.x * w0 + bq.x * w1) * inv, (a.y * w0 + bq.y * w1) * inv,
                (a.z * w0 + bq.z * w1) * inv, (a.w * w0 + bq.w * w1) * inv};
  unsigned h[4], lo[4];
  #pragma unroll
  for (int j = 0; j < 4; ++j) {
    h[j] = bf_hi(o[j]);
    lo[j] = bf_hi(o[j] - bf_to_f(h[j]));
  }
  const size_t rowo = (size_t)s * ATT_N + head * 256 + lane * 4;
  *(uint2*)(Oh + rowo) = make_uint2(h[0] | (h[1] << 16), h[2] | (h[3] << 16));
  *(uint2*)(Ol + rowo) = make_uint2(lo[0] | (lo[1] << 16), lo[2] | (lo[3] << 16));
}

extern "C" void kernel_launch(void* const* d_in, const int* in_sizes, int n_in,
                              void* d_out, int out_size, void* d_ws, size_t ws_size,
                              hipStream_t stream) {
  const float* hs    = (const float*)d_in[0];
  const float* cosp  = (const float*)d_in[1];
  const float* sinp  = (const float*)d_in[2];
  const float* w_qkv = (const float*)d_in[3];   // (2560, 4096)
  const float* w_o   = (const float*)d_in[4];   // (2048, 2560)
  const float* qw    = (const float*)d_in[5];
  const float* kw    = (const float*)d_in[6];

  const size_t MB = 1024 * 1024;
  char* ws = (char*)d_ws;
  // workspace map (peak 72 MiB, liveness-overlaid):
  float* qkv = (float*)ws;                               // [0,32M): gemm1 out, dead after preps
  unsigned short* wh = (unsigned short*)(ws + 32 * MB);  // [32,52M): w_qkv hi, dead after gemm1
  unsigned short* wl = (unsigned short*)(ws + 52 * MB);  // [52,72M)
  unsigned short* Qh = (unsigned short*)(ws + 32 * MB);  // [32,40M), dead after attn
  unsigned short* Ql = (unsigned short*)(ws + 40 * MB);  // [40,48M)
  unsigned short* Kh = (unsigned short*)(ws + 48 * MB);  // [48,52M)
  unsigned short* Kl = (unsigned short*)(ws + 52 * MB);  // [52,56M)
  unsigned short* VTh = (unsigned short*)(ws + 56 * MB); // [56,60M)
  unsigned short* VTl = (unsigned short*)(ws + 60 * MB); // [60,64M)
  float* O0 = (float*)ws;                                // [0,16M): qkv dead by then
  float* MLp = (float*)(ws + 16 * MB);                   // [16,16.25M)
  unsigned short* Oh = (unsigned short*)(ws + 32 * MB);  // [32,40M): Qh dead after attn
  unsigned short* Ol = (unsigned short*)(ws + 40 * MB);  // [40,48M)
  unsigned short* oh = (unsigned short*)(ws + 48 * MB);  // [48,58M): K/VT dead
  unsigned short* ol = (unsigned short*)(ws + 58 * MB);  // [58,68M)
  // d_out doubles as scratch: hs split (dead after gemm1), then khalf-1 partial
  unsigned short* Ahs = (unsigned short*)d_out;
  unsigned short* Als = Ahs + (size_t)S_LEN * HID;
  float* O1 = (float*)d_out;                             // 16M of 20.97M
  float* out = (float*)d_out;

  // 1) hs -> split bf16 (into d_out scratch)
  split_rows<<<(S_LEN * HID) / (256 * 8), 256, 0, stream>>>(hs, Ahs, Als);
  // 2) w_qkv -> split^T
  split_transpose<<<dim3(QKV_N / 32, HID / 32), 256, 0, stream>>>(
      w_qkv, wh, wl, HID, QKV_N);
  // 3) qkv = hs @ w_qkv  (2-phase double-buffered split MFMA)
  gemm_bf16_split<<<(S_LEN / 128) * (QKV_N / 128), 256, 0, stream>>>(
      Ahs, Als, wh, wl, qkv, S_LEN, QKV_N, HID, QKV_N / 128);
  // 4) norm+rope -> Q/K split bf16 (SCALE folded into Q)
  qk_norm_rope_split<<<(S_LEN * 12) / 4, 256, 0, stream>>>(
      qkv, cosp, sinp, qw, kw, Qh, Ql, Kh, Kl);
  // 5) V -> split + transpose
  v_split_transpose<<<dim3(S_LEN / 32, 256 / 32, 4), 256, 0, stream>>>(
      qkv, VTh, VTl);
  // 6) split-K attention partials (K staged, V L2-direct, XCD-affine)
  attn_part<<<1024, 128, 0, stream>>>(Qh, Ql, Kh, Kl, VTh, VTl, O0, O1, MLp);
  // 7) combine -> split-bf16 attn output (over dead Qh/Ql)
  attn_combine<<<(S_LEN * NHQ) / 4, 256, 0, stream>>>(O0, O1, MLp, Oh, Ol);
  // 8) w_o -> split^T (over dead K/VT)
  split_transpose<<<dim3(HID / 32, ATT_N / 32), 256, 0, stream>>>(
      w_o, oh, ol, ATT_N, HID);
  // 9) out = attn @ w_o
  gemm_bf16_split<<<(S_LEN / 128) * (HID / 128), 256, 0, stream>>>(
      Oh, Ol, oh, ol, out, S_LEN, HID, ATT_N, HID / 128);
}